// Round 1
// baseline (791.091 us; speedup 1.0000x reference)
//
#include <hip/hip_runtime.h>
#include <cmath>
#include <cstdint>
#include <vector>

#define WGB 256

// ---------------- constexpr problem metadata (evaluated identically host+device) ----------------
struct TripleMeta { int l,l1,l2,d,d1,d2,form,dp4,cgR,cgL,xl,uv; };
struct AllMeta { TripleMeta t[48]; int nT, cgTotal, xlTotal, uvTotal; };

constexpr AllMeta build_meta() {
  AllMeta M{};
  const int LSl[5] = {0,2,4,6,8};
  int k=0, cg=0;
  for (int a=0;a<5;a++){ const int l=LSl[a];
    for (int b=0;b<5;b++){ const int l1=LSl[b];
      for (int l2=l1;l2<=8;l2+=2){
        if (!((l2-l1)<=l && l<=(l1+l2))) continue;
        TripleMeta m{};
        m.l=l; m.l1=l1; m.l2=l2;
        m.d=2*l+1; m.d1=2*l1+1; m.d2=2*l2+1;
        m.form = (l1==0) ? ((l2==0)?2:1) : 0;   // 0=A (l1>0), 1=B (l1==0,l2>0), 2=D (0,0,0)
        m.dp4 = ((m.d+3)/4)*4;
        m.cgR = cg; cg += m.d*m.d1*m.d2;
        M.t[k] = m; k++;
      } } }
  M.nT=k; M.cgTotal=cg;
  int cgl=cg;
  for (int i=0;i<k;i++){ M.t[i].cgL=cgl; cgl += M.t[i].d*M.t[i].d1*M.t[i].d2; }
  int xl=0, uv=0;
  for (int i=0;i<k;i++){
    if (M.t[i].form==0){ M.t[i].xl=xl; xl += 2*M.t[i].d*M.t[i].d2; M.t[i].uv=uv; uv += 4*M.t[i].dp4; }
    else if (M.t[i].form==1){ M.t[i].xl=0; M.t[i].uv=uv; uv += 2*M.t[i].dp4; }
  }
  M.xlTotal=xl; M.uvTotal=uv;
  return M;
}

constexpr AllMeta META_H = build_meta();            // host view
static_assert(META_H.nT==42, "nT");
static_assert(META_H.cgTotal==52334, "cgTotal");
static_assert(META_H.xlTotal==10146, "xlTotal");
static_assert(META_H.uvTotal==2048, "uvTotal");
static_assert(META_H.t[5].l==2 && META_H.t[13].l==4 && META_H.t[23].l==6 && META_H.t[33].l==8, "grp");

__device__ constexpr AllMeta META = build_meta();   // device view (identical values)

constexpr int CG_TOTAL  = 52334;
constexpr int CG_TOTAL2 = 2*CG_TOTAL;
constexpr int UVS       = 2048;      // U/V slot-table stride (floats) per (ab,c)
constexpr int XLTOT     = 10146;

__device__ constexpr int XOFS_T[5] = {0,8,18,36,62};          // x LDS offsets per l/2
__device__ constexpr int DL[5]     = {1,5,9,13,17};
__device__ constexpr int T0G[6]    = {0,5,13,23,33,42};       // triple ranges per output-l group
__device__ constexpr int RHNB[5]   = {163840,196608,1015808,3670016,9207808}; // rh_n out offsets
__device__ constexpr int CBASE[5]  = {352,312,240,136,0};     // phase-3 column base per li

// ---------------- kernel 1: V table per (ab,c) ----------------
// V_{t,p,q}[k2] = sum_a w_l1[p,c,a] * sum_j w_l2[q,c,j] * R_t[k2,a,j]
__global__ __launch_bounds__(WGB) void s2_prep(
    const float* __restrict__ w2, const float* __restrict__ w4,
    const float* __restrict__ w6, const float* __restrict__ w8,
    const float* __restrict__ cg, float* __restrict__ V)
{
  const int ab = blockIdx.x >> 3;
  const int c  = blockIdx.x & 7;
  float* Vb = V + blockIdx.x * UVS;
  const float* ws[4] = {w2,w4,w6,w8};
  #pragma unroll
  for (int t=0;t<42;t++){
    const auto &m = META.t[t];
    if (m.form==0){
      const float* w1p = ws[(m.l1>>1)-1];
      const float* w2p = ws[(m.l2>>1)-1];
      for (int idx=threadIdx.x; idx<4*m.d; idx+=WGB){
        const int pq = idx / m.d;
        const int k2 = idx - pq*m.d;
        const int p = pq>>1, q = pq&1;
        const float* R  = cg + m.cgR + k2*(m.d1*m.d2);
        const float* wA = w1p + ((ab*2+p)*8 + c)*m.d1;
        const float* wB = w2p + ((ab*2+q)*8 + c)*m.d2;
        float s = 0.f;
        for (int al=0; al<m.d1; al++){
          float wr = 0.f;
          for (int j=0;j<m.d2;j++) wr += wB[j]*R[al*m.d2+j];
          s += wA[al]*wr;
        }
        Vb[m.uv + pq*m.dp4 + k2] = s;
      }
    } else if (m.form==1){
      const float* w2p = ws[(m.l2>>1)-1];
      for (int idx=threadIdx.x; idx<2*m.d; idx+=WGB){
        const int q  = idx / m.d;
        const int k2 = idx - q*m.d;
        const float* R  = cg + m.cgR + k2*m.d2;   // d1==1
        const float* wB = w2p + ((ab*2+q)*8 + c)*m.d2;
        float s = 0.f;
        for (int j=0;j<m.d2;j++) s += wB[j]*R[j];
        Vb[m.uv + q*m.dp4 + k2] = s;
      }
    }
  }
}

// ---------------- phase-3 column worker (one (c, l, k2) column) ----------------
template<int LI>
__device__ __forceinline__ float col_work(int k2, float rh0c, float c000,
    const float* __restrict__ Vc, const float* Ush,
    float* __restrict__ out, int ob)
{
  constexpr int d   = (LI==0)?1:(LI==1)?5:(LI==2)?9:(LI==3)?13:17;
  constexpr int np4 = (d+3)/4;
  float4 za[np4];
  #pragma unroll
  for (int i=0;i<np4;i++) za[i] = make_float4(0.f,0.f,0.f,0.f);
  #pragma unroll
  for (int t=T0G[LI]; t<T0G[LI+1]; t++){
    const auto &m = META.t[t];
    if (m.form==2){
      za[0].x += rh0c*rh0c*c000;
    } else {
      const int npr = (m.form==0)?4:2;
      #pragma unroll
      for (int pr=0;pr<npr;pr++){
        float v = Vc[m.uv + pr*m.dp4 + k2];
        if (m.form==1) v *= rh0c;
        const float4* Up = reinterpret_cast<const float4*>(Ush + m.uv + pr*m.dp4);
        #pragma unroll
        for (int rr=0;rr<np4;rr++){
          float4 u = Up[rr];           // wave-uniform LDS broadcast
          za[rr].x += u.x*v; za[rr].y += u.y*v; za[rr].z += u.z*v; za[rr].w += u.w*v;
        }
      }
    }
  }
  float s = 0.f;
  #pragma unroll
  for (int rr=0;rr<np4;rr++){
    const float vals[4] = {za[rr].x, za[rr].y, za[rr].z, za[rr].w};
    #pragma unroll
    for (int e=0;e<4;e++){
      const int k1 = 4*rr+e;
      if (k1 < d){
        out[ob + k1*d + k2] = vals[e];
        s += vals[e]*vals[e];
      }
    }
  }
  return s;
}

// ---------------- kernel 2: main, one block per (ab,n) ----------------
__global__ __launch_bounds__(WGB) void s2_main(
    const float* __restrict__ x0, const float* __restrict__ x2, const float* __restrict__ x4,
    const float* __restrict__ x6, const float* __restrict__ x8,
    const float* __restrict__ w0, const float* __restrict__ bias,
    const float* __restrict__ cg, const float* __restrict__ cgt,
    const float* __restrict__ V, float* __restrict__ out, float c000)
{
  __shared__ float xb[96];
  __shared__ float rh0s[8];
  __shared__ float XL[XLTOT];
  __shared__ alignas(16) float U[UVS];
  __shared__ float fpart[360];
  const int tid = threadIdx.x;
  const int bid = blockIdx.x;
  const int ab  = bid >> 10;
  const int n   = bid & 1023;

  // ---- phase 0: stage x, compute rh0 (= x0·w0 + bias, the l=0 conv scalar) ----
  if (tid < 5)        xb[tid]           = x0[bid*5  + tid];
  else if (tid < 15)  xb[8  + (tid-5)]  = x2[bid*10 + (tid-5)];
  else if (tid < 33)  xb[18 + (tid-15)] = x4[bid*18 + (tid-15)];
  else if (tid < 59)  xb[36 + (tid-33)] = x6[bid*26 + (tid-33)];
  else if (tid < 93)  xb[62 + (tid-59)] = x8[bid*34 + (tid-59)];
  else if (tid >= 96 && tid < 104) {
    const int c = tid - 96;
    float s = bias[ab*8 + c];
    for (int i=0;i<5;i++) s += x0[bid*5+i] * w0[(ab*5+i)*8 + c];
    rh0s[c] = s;
  }
  __syncthreads();

  // ---- phase 1: XL_{t,p}[k1,b] = sum_j x_l1[p,j]*L_t[k1,b,j] (FormA, transposed CG for coalescing)
  //               U'_{t,q}[k1]   = sum_b L_t[k1,b,0]*x_l2[q,b]  (FormB) ----
  #pragma unroll
  for (int t=0;t<42;t++){
    const auto &m = META.t[t];
    if (m.form==0){
      const int dd2 = m.d*m.d2;
      const float* LT  = cgt + m.cgR;              // LT[j][r], r = k1*d2+b
      const int xo1 = XOFS_T[m.l1>>1];
      for (int idx=tid; idx<2*dd2; idx+=WGB){
        const int p = (idx>=dd2) ? 1 : 0;
        const int r = idx - p*dd2;
        const float* xp = xb + xo1 + p*m.d1;
        float s = 0.f;
        for (int j=0;j<m.d1;j++) s += xp[j]*LT[j*dd2 + r];
        XL[m.xl + p*dd2 + r] = s;
      }
    } else if (m.form==1){
      const float* Lt = cg + m.cgL;                // L[k1,b,0] flat = k1*d2+b
      const int xo2 = XOFS_T[m.l2>>1];
      for (int idx=tid; idx<2*m.d; idx+=WGB){
        const int q  = (idx>=m.d) ? 1 : 0;
        const int k1 = idx - q*m.d;
        float s = 0.f;
        for (int b2=0;b2<m.d2;b2++) s += Lt[k1*m.d2 + b2] * xb[xo2 + q*m.d2 + b2];
        U[m.uv + q*m.dp4 + k1] = s;
      }
    }
  }
  __syncthreads();

  // ---- phase 2: U_{t,p,q}[k1] = sum_b XL_{t,p}[k1,b] * x_l2[q,b] (FormA) ----
  #pragma unroll
  for (int t=0;t<42;t++){
    const auto &m = META.t[t];
    if (m.form!=0) continue;
    const int xo2 = XOFS_T[m.l2>>1];
    for (int idx=tid; idx<4*m.d; idx+=WGB){
      const int pq = idx / m.d;
      const int k1 = idx - pq*m.d;
      const int p = pq>>1, q = pq&1;
      const float* xlr = XL + m.xl + (p*m.d + k1)*m.d2;
      const float* xq  = xb + xo2 + q*m.d2;
      float s = 0.f;
      for (int b2=0;b2<m.d2;b2++) s += xlr[b2]*xq[b2];
      U[m.uv + pq*m.dp4 + k1] = s;
    }
  }
  __syncthreads();

  // ---- phase 3: z_l[k1,k2] = sum over (t,p,q) of U[k1]*V[k2] ; store rh_n + feats partials ----
  const float* Vab = V + (ab*8)*UVS;
  for (int col=tid; col<360; col+=WGB){
    int li, c, k2;
    if (col < 136)      { li=4; c = col/17;            k2 = col - c*17; }
    else if (col < 240) { const int r=col-136; li=3; c=r/13; k2=r-c*13; }
    else if (col < 312) { const int r=col-240; li=2; c=r/9;  k2=r-c*9;  }
    else if (col < 352) { const int r=col-312; li=1; c=r/5;  k2=r-c*5;  }
    else                { li=0; c=col-352; k2=0; }
    const int d = DL[li];
    const float rh0c = rh0s[c];
    const float* Vc = Vab + c*UVS;
    const int ob = RHNB[li] + (bid*8+c)*d*d;
    float s;
    switch(li){
      case 4:  s = col_work<4>(k2, rh0c, c000, Vc, U, out, ob); break;
      case 3:  s = col_work<3>(k2, rh0c, c000, Vc, U, out, ob); break;
      case 2:  s = col_work<2>(k2, rh0c, c000, Vc, U, out, ob); break;
      case 1:  s = col_work<1>(k2, rh0c, c000, Vc, U, out, ob); break;
      default: s = col_work<0>(k2, rh0c, c000, Vc, U, out, ob); break;
    }
    fpart[col] = s;
  }
  __syncthreads();

  // ---- phase 4: feats reduce: n_l * sum_{k1,k2} z^2, layout (A,B, 5*N*C) ----
  if (tid < 40){
    const int c = tid/5, li = tid%5;
    const int d = DL[li];
    float s = 0.f;
    for (int k2=0;k2<d;k2++) s += fpart[CBASE[li] + c*d + k2];
    const double nl_d = 8.0*3.14159265358979323846*3.14159265358979323846/(double)(2*(2*li)+1);
    out[ab*40960 + li*8192 + n*8 + c] = (float)nl_d * s;
  }
}

// ---------------- host: numpy MT19937 + legacy gauss, CG upload at dlopen ----------------
namespace {

struct MTRng {
  uint32_t mt[624]; int mti;
  bool has_g; double g;
  void seed(uint32_t s){
    for (int pos=0; pos<624; pos++){ mt[pos]=s; s = 1812433253u*(s^(s>>30)) + (uint32_t)pos + 1u; }
    mti = 624; has_g=false; g=0.0;
  }
  uint32_t next32(){
    if (mti >= 624){
      for (int i=0;i<624;i++){
        uint32_t y = (mt[i]&0x80000000u) | (mt[(i+1)%624]&0x7fffffffu);
        mt[i] = mt[(i+397)%624] ^ (y>>1) ^ ((y&1u) ? 0x9908b0dfu : 0u);
      }
      mti = 0;
    }
    uint32_t y = mt[mti++];
    y ^= y>>11; y ^= (y<<7)&0x9d2c5680u; y ^= (y<<15)&0xefc60000u; y ^= y>>18;
    return y;
  }
  double rk_double(){
    uint32_t a = next32()>>5, b = next32()>>6;
    return (a*67108864.0 + b)/9007199254740992.0;
  }
  double gauss(){
    if (has_g){ has_g=false; return g; }
    double f,x1,x2,r2;
    do {
      x1 = 2.0*rk_double()-1.0;
      x2 = 2.0*rk_double()-1.0;
      r2 = x1*x1 + x2*x2;
    } while (r2 >= 1.0 || r2 == 0.0);
    f = std::sqrt(-2.0*std::log(r2)/r2);
    g = f*x1; has_g = true;
    return f*x2;
  }
};

struct DeviceSetup {
  float* d_cg  = nullptr;   // [CG_R | CG_L]
  float* d_cgt = nullptr;   // CG_L transposed per triple: LT[j][k1*d2+b]
  float* d_v   = nullptr;   // 32 * UVS floats, rewritten by s2_prep every launch
  float  c000  = 0.f;
  DeviceSetup(){
    std::vector<float> h(CG_TOTAL2);
    MTRng r; r.seed(42u);
    for (int i=0;i<CG_TOTAL2;i++) h[i] = (float)(r.gauss()*0.1);
    std::vector<float> hT(CG_TOTAL, 0.f);
    for (int t=0;t<META_H.nT;t++){
      const TripleMeta &m = META_H.t[t];
      const int dd2 = m.d*m.d2;
      for (int rr=0; rr<dd2; rr++)
        for (int j=0; j<m.d1; j++)
          hT[m.cgR + j*dd2 + rr] = h[m.cgL + rr*m.d1 + j];
    }
    c000 = h[META_H.t[0].cgL] * h[META_H.t[0].cgR];
    (void)hipMalloc((void**)&d_cg,  sizeof(float)*CG_TOTAL2);
    (void)hipMalloc((void**)&d_cgt, sizeof(float)*CG_TOTAL);
    (void)hipMalloc((void**)&d_v,   sizeof(float)*32*UVS);
    (void)hipMemcpy(d_cg,  h.data(),  sizeof(float)*CG_TOTAL2, hipMemcpyHostToDevice);
    (void)hipMemcpy(d_cgt, hT.data(), sizeof(float)*CG_TOTAL,  hipMemcpyHostToDevice);
  }
};
DeviceSetup g_dev;   // static init at dlopen: pure-CPU RNG + one-time uploads (outside graph capture)

} // namespace

extern "C" void kernel_launch(void* const* d_in, const int* in_sizes, int n_in,
                              void* d_out, int out_size, void* d_ws, size_t ws_size,
                              hipStream_t stream)
{
  (void)in_sizes; (void)n_in; (void)d_ws; (void)ws_size; (void)out_size;
  const float* x0   = (const float*)d_in[0];
  const float* w0   = (const float*)d_in[1];
  const float* x2   = (const float*)d_in[2];
  const float* w2   = (const float*)d_in[3];
  const float* x4   = (const float*)d_in[4];
  const float* w4   = (const float*)d_in[5];
  const float* x6   = (const float*)d_in[6];
  const float* w6   = (const float*)d_in[7];
  const float* x8   = (const float*)d_in[8];
  const float* w8   = (const float*)d_in[9];
  const float* bias = (const float*)d_in[10];
  float* out = (float*)d_out;

  s2_prep<<<dim3(32),   dim3(WGB), 0, stream>>>(w2,w4,w6,w8, g_dev.d_cg, g_dev.d_v);
  s2_main<<<dim3(4096), dim3(WGB), 0, stream>>>(x0,x2,x4,x6,x8, w0, bias,
                                                g_dev.d_cg, g_dev.d_cgt, g_dev.d_v,
                                                out, g_dev.c000);
}